// Round 1
// baseline (965.958 us; speedup 1.0000x reference)
//
#include <hip/hip_runtime.h>

// Reference constants
constexpr int   TH    = 8;     // TREE_HEIGHT
constexpr int   NNEG  = 8;     // N_NEG
constexpr int   HID4  = 256;   // HIDDEN in float4 units (1024/4)
constexpr int   HALF4 = 128;   // SINGLE_DIM in float4 units (512/4)
constexpr float SCR_F = 6.2831853071795864769f; // 2*pi

__global__ void zero_kernel(float* out) { out[0] = 0.0f; }

// One block per batch element. 128 threads; thread t owns columns [4t, 4t+4)
// of the 512-wide folded output. Key algebraic identity: emb[p1] cancels
// between pos_dist and neg_dist, so only p2 (8 rows) and neg (64 rows) are
// gathered: 72 rows x 4KB = 288KB/block, fully coalesced float4.
__global__ __launch_bounds__(128)
void punish_kernel(const float* __restrict__ emb,
                   const int*   __restrict__ pos_path,
                   const int*   __restrict__ neg_path,
                   float*       __restrict__ out)
{
    const int b = blockIdx.x;
    const int t = threadIdx.x;          // 0..127

    __shared__ int   s_p1[TH];
    __shared__ int   s_p2[TH];
    __shared__ int   s_neg[NNEG * TH];
    __shared__ float s_C[NNEG];
    __shared__ float s_red[2][NNEG];    // per-wave partial sums

    if (t < TH) {
        s_p1[t] = pos_path[b * 2 * TH + t];
        s_p2[t] = pos_path[b * 2 * TH + TH + t];
    }
    if (t < NNEG * TH) {
        s_neg[t] = neg_path[b * NNEG * TH + t];
    }
    __syncthreads();

    // Constant term per negative: C[n] = (diff_pos - 1 - (raw_n==0)) * 2pi
    if (t < NNEG) {
        int inter_pos = 0;
#pragma unroll
        for (int i = 0; i < TH; i++) {
            const int v = s_p1[i];
            bool f = false;
#pragma unroll
            for (int j = 0; j < TH; j++) f = f || (v == s_p2[j]);
            inter_pos += f ? 1 : 0;
        }
        const float diff_pos = fmaxf((float)(TH - inter_pos), 1.0f);

        const int n = t;
        int inter_n = 0;
#pragma unroll
        for (int i = 0; i < TH; i++) {
            const int v = s_p1[i];
            bool f = false;
#pragma unroll
            for (int j = 0; j < TH; j++) f = f || (v == s_neg[n * TH + j]);
            inter_n += f ? 1 : 0;
        }
        const int raw = TH - inter_n;   // diff_neg_raw (integer, >= 0)
        s_C[n] = (diff_pos - 1.0f - (raw == 0 ? 1.0f : 0.0f)) * SCR_F;
    }
    __syncthreads();

    const float4* __restrict__ embv = (const float4*)emb;

    // Sum of p2 rows (low half + high half folded)
    float4 sp2 = {0.f, 0.f, 0.f, 0.f};
#pragma unroll
    for (int h = 0; h < TH; h++) {
        const float4* row = embv + (long)s_p2[h] * HID4;
        const float4 lo = row[t];
        const float4 hi = row[HALF4 + t];
        sp2.x += lo.x + hi.x;
        sp2.y += lo.y + hi.y;
        sp2.z += lo.z + hi.z;
        sp2.w += lo.w + hi.w;
    }

    // Per-negative sums, then relu^2 partial reductions
    float a[NNEG];
#pragma unroll
    for (int n = 0; n < NNEG; n++) {
        float4 sn = {0.f, 0.f, 0.f, 0.f};
#pragma unroll
        for (int h = 0; h < TH; h++) {
            const float4* row = embv + (long)s_neg[n * TH + h] * HID4;
            const float4 lo = row[t];
            const float4 hi = row[HALF4 + t];
            sn.x += lo.x + hi.x;
            sn.y += lo.y + hi.y;
            sn.z += lo.z + hi.z;
            sn.w += lo.w + hi.w;
        }
        const float c = s_C[n];
        float vx = c + 0.5f * (sn.x - sp2.x);
        float vy = c + 0.5f * (sn.y - sp2.y);
        float vz = c + 0.5f * (sn.z - sp2.z);
        float vw = c + 0.5f * (sn.w - sp2.w);
        vx = fmaxf(vx, 0.f); vy = fmaxf(vy, 0.f);
        vz = fmaxf(vz, 0.f); vw = fmaxf(vw, 0.f);
        a[n] = vx * vx + vy * vy + vz * vz + vw * vw;
    }

    // Wave-64 butterfly reduce each of the 8 sums
#pragma unroll
    for (int n = 0; n < NNEG; n++) {
#pragma unroll
        for (int off = 32; off > 0; off >>= 1) {
            a[n] += __shfl_down(a[n], off, 64);
        }
    }
    const int lane = t & 63;
    const int wid  = t >> 6;            // 0 or 1
    if (lane == 0) {
#pragma unroll
        for (int n = 0; n < NNEG; n++) s_red[wid][n] = a[n];
    }
    __syncthreads();

    if (t == 0) {
        float total = 0.f;
#pragma unroll
        for (int n = 0; n < NNEG; n++) {
            total += sqrtf(s_red[0][n] + s_red[1][n]);
        }
        atomicAdd(out, total);
    }
}

extern "C" void kernel_launch(void* const* d_in, const int* in_sizes, int n_in,
                              void* d_out, int out_size, void* d_ws, size_t ws_size,
                              hipStream_t stream) {
    const float* emb      = (const float*)d_in[0];
    const int*   pos_path = (const int*)d_in[1];
    const int*   neg_path = (const int*)d_in[2];
    float*       out      = (float*)d_out;

    const int BATCH = in_sizes[1] / (2 * TH);   // 2048

    zero_kernel<<<1, 1, 0, stream>>>(out);
    punish_kernel<<<BATCH, 128, 0, stream>>>(emb, pos_path, neg_path, out);
}